// Round 11
// baseline (424.169 us; speedup 1.0000x reference)
//
#include <hip/hip_runtime.h>
#include <hip/hip_bf16.h>
#include <hip/hip_fp16.h>
#include <math.h>

#define N_NODES_C 50000
#define NBKT ((N_NODES_C + 255) / 256)   // 196 buckets of 256 nodes
#define NEG_SLOPE 0.2f
#define EPS_ 1e-16f

typedef _Float16 f16x8 __attribute__((ext_vector_type(8)));
typedef float    f32x4 __attribute__((ext_vector_type(4)));

__device__ __forceinline__ float lrelu(float x){ return x > 0.f ? x : NEG_SLOPE * x; }

// ---------------- CSR build ----------------
__global__ void cinit_k(int* __restrict__ counts, int n){
  int t = blockIdx.x * blockDim.x + threadIdx.x;
  if (t < n) counts[t] = 1;              // self-loop baseline
}

__global__ void hist_k(const int* __restrict__ dstv, int* __restrict__ counts, int E){
  int t = blockIdx.x * blockDim.x + threadIdx.x;
  if (t < E) atomicAdd(&counts[dstv[t]], 1);
}

__global__ void chunksum_k(const int* __restrict__ counts, int* __restrict__ sums, int n){
  __shared__ int lds[4];
  int base = blockIdx.x * 1024;
  int t = threadIdx.x; // 256
  int s = 0;
  for (int i = t; i < 1024; i += 256){ int idx = base + i; s += (idx < n) ? counts[idx] : 0; }
  for (int d = 32; d >= 1; d >>= 1) s += __shfl_xor(s, d);
  if ((t & 63) == 0) lds[t >> 6] = s;
  __syncthreads();
  if (t == 0) sums[blockIdx.x] = lds[0] + lds[1] + lds[2] + lds[3];
}

// scan with fused chunk-offset (csums sum) and bcur init. nch <= 64.
__global__ void scan_k(const int* __restrict__ counts, const int* __restrict__ csums,
                       int* __restrict__ row_ptr, int* __restrict__ bcur, int nch, int n){
  __shared__ int ws[16];
  __shared__ int boff;
  int base = blockIdx.x * 1024; int t = threadIdx.x; int idx = base + t;
  int v = (idx < n) ? counts[idx] : 0;
  int lane = t & 63, wid = t >> 6;
  int x = v;
  for (int d = 1; d < 64; d <<= 1){ int y = __shfl_up(x, d); if (lane >= d) x += y; }
  if (lane == 63) ws[wid] = x;
  if (t < 64){
    int c = (t < blockIdx.x) ? csums[t] : 0;
    for (int d = 32; d >= 1; d >>= 1) c += __shfl_xor(c, d);
    if (t == 0) boff = c;
  }
  __syncthreads();
  if (t < 16){ int y = ws[t]; for (int d = 1; d < 16; d <<= 1){ int z = __shfl_up(y, d); if (t >= d) y += z; } ws[t] = y; }
  __syncthreads();
  int excl = x - v + (wid ? ws[wid - 1] : 0) + boff;
  if (idx < n){
    row_ptr[idx] = excl;
    if ((idx & 255) == 0) bcur[idx >> 8] = excl;
  }
  if (blockIdx.x == nch - 1 && t == 0) row_ptr[n] = boff + ws[15];
}

// phase 1: classify edges (real + self) into dst-buckets with LDS staging.
// entry = src | (dst & 255) << 16
#define BATCH 2048
#define BCAP 32
__global__ __launch_bounds__(256) void bucket_k(const int* __restrict__ srcv, const int* __restrict__ dstv,
                                                int* __restrict__ bcur, unsigned* __restrict__ ebuf,
                                                int E, int n){
  __shared__ unsigned stage[NBKT * BCAP];   // 25 KB
  __shared__ int cnt[NBKT];
  int t = threadIdx.x;
  int tot = E + n;
  int start = blockIdx.x * BATCH;
  int end = start + BATCH; if (end > tot) end = tot;
  for (int i = t; i < NBKT; i += 256) cnt[i] = 0;
  __syncthreads();
  for (int idx = start + t; idx < end; idx += 256){
    int s, d;
    if (idx < E){ s = srcv[idx]; d = dstv[idx]; }
    else { s = idx - E; d = s; }
    int b = d >> 8;
    unsigned entry = (unsigned)s | ((unsigned)(d & 255) << 16);
    int pos = atomicAdd(&cnt[b], 1);
    if (pos < BCAP) stage[b * BCAP + pos] = entry;
    else { int p = atomicAdd(&bcur[b], 1); ebuf[p] = entry; }   // overflow path
  }
  __syncthreads();
  if (t < NBKT){
    int c = cnt[t]; if (c > BCAP) c = BCAP;
    if (c > 0){
      int p = atomicAdd(&bcur[t], c);
      for (int i = 0; i < c; i++) ebuf[p + i] = stage[t * BCAP + i];
    }
  }
}

// phase 2: one block owns one bucket; rank edges per node; KEEP the packed entry.
__global__ __launch_bounds__(256) void bsort_k(const unsigned* __restrict__ ebuf,
                                               const int* __restrict__ row_ptr,
                                               int* __restrict__ esrc, int n){
  __shared__ int cnt[256];
  int b = blockIdx.x;
  int nb = b * 256;
  int t = threadIdx.x;
  cnt[t] = 0;
  __syncthreads();
  int hi_node = nb + 256; if (hi_node > n) hi_node = n;
  int beg = row_ptr[nb], end = row_ptr[hi_node];
  for (int i = beg + t; i < end; i += 256){
    unsigned e = ebuf[i];
    int dl = e >> 16;
    int rank = atomicAdd(&cnt[dl], 1);
    esrc[row_ptr[nb + dl] + rank] = (int)e;   // keep (dl<<16)|src
  }
}

// ---------------- W repack to MFMA B-fragment order (fp16), all 3 in one launch ----------------
template<int K, int J>
__device__ void wpack_dev(const float* __restrict__ W, uint4* __restrict__ Wf, int blk, int nblk){
  constexpr int KS = K / 32, NT = J / 16;
  int tot = KS * NT * 64;
  for (int t = blk * 256 + threadIdx.x; t < tot; t += nblk * 256){
    int l = t & 63;
    int nt = (t >> 6) % NT;
    int kk = t / (64 * NT);
    int col = nt * 16 + (l & 15);
    int k0 = kk * 32 + (l >> 4) * 8;
    unsigned u[4];
    #pragma unroll
    for (int p = 0; p < 4; p++){
      __half2 h = __floats2half2_rn(W[(k0 + 2 * p) * J + col], W[(k0 + 2 * p + 1) * J + col]);
      u[p] = *reinterpret_cast<unsigned*>(&h);
    }
    uint4 v; v.x = u[0]; v.y = u[1]; v.z = u[2]; v.w = u[3];
    Wf[t] = v;
  }
}

__global__ void wpack_all_k(const float* W1, const float* W2, const float* W3,
                            uint4* Wf1, uint4* Wf2, uint4* Wf3){
  int b = blockIdx.x;
  if (b < 6) wpack_dev<128, 96>(W1, Wf1, b, 6);
  else if (b < 11) wpack_dev<96, 96>(W2, Wf2, b - 6, 5);
  else wpack_dev<96, 128>(W3, Wf3, b - 11, 6);
}

// ---------------- MFMA GEMM + alpha ----------------
template<int K, int J, int HEADS, bool AF16>
__global__ __launch_bounds__(256) void gemm_mfma_k(
    const void* __restrict__ Ain, const uint4* __restrict__ Wf,
    const float* __restrict__ a_s, const float* __restrict__ a_d,
    __half* __restrict__ Hh, float* __restrict__ asrc, float* __restrict__ adst, int n){
  constexpr int KS = K / 32;
  constexpr int NT = J / 16;
  constexpr int CPR = K / 8;
  constexpr int NTPH = NT / HEADS;
  __shared__ uint4 Alds[64 * 16];
  int t = threadIdx.x;
  int rbase = blockIdx.x * 64;

  for (int i = t; i < 64 * CPR; i += 256){
    int r = i / CPR, c = i % CPR;
    int gr = rbase + r;
    uint4 v = make_uint4(0u, 0u, 0u, 0u);
    if (gr < n){
      if (AF16){
        v = ((const uint4*)Ain)[(size_t)gr * CPR + c];
      } else {
        const float4* af = (const float4*)Ain + (size_t)gr * (K / 4) + c * 2;
        float4 lo = af[0], hi = af[1];
        __half2 p0 = __floats2half2_rn(lo.x, lo.y);
        __half2 p1 = __floats2half2_rn(lo.z, lo.w);
        __half2 p2 = __floats2half2_rn(hi.x, hi.y);
        __half2 p3 = __floats2half2_rn(hi.z, hi.w);
        v.x = *reinterpret_cast<unsigned*>(&p0);
        v.y = *reinterpret_cast<unsigned*>(&p1);
        v.z = *reinterpret_cast<unsigned*>(&p2);
        v.w = *reinterpret_cast<unsigned*>(&p3);
      }
    }
    Alds[r * 16 + (c ^ (r & 7))] = v;
  }
  __syncthreads();

  int l = t & 63;
  int wrow = (t >> 6) * 16;
  int sub = l & 15;
  int lk = l >> 4;
  f32x4 acc[NT];
  #pragma unroll
  for (int i = 0; i < NT; i++) acc[i] = (f32x4){0.f, 0.f, 0.f, 0.f};

  for (int kk = 0; kk < KS; kk++){
    int trow = wrow + sub;
    int c = kk * 4 + lk;
    f16x8 a = *reinterpret_cast<const f16x8*>(&Alds[trow * 16 + (c ^ (trow & 7))]);
    const uint4* wb = Wf + (size_t)(kk * NT) * 64 + l;
    #pragma unroll
    for (int nt = 0; nt < NT; nt++){
      uint4 wv = wb[nt * 64];
      f16x8 bfr = *reinterpret_cast<const f16x8*>(&wv);
      acc[nt] = __builtin_amdgcn_mfma_f32_16x16x32_f16(a, bfr, acc[nt], 0, 0, 0);
    }
  }

  float ps[HEADS][4], pd[HEADS][4];
  #pragma unroll
  for (int h = 0; h < HEADS; h++)
    #pragma unroll
    for (int r = 0; r < 4; r++){ ps[h][r] = 0.f; pd[h][r] = 0.f; }
  #pragma unroll
  for (int nt = 0; nt < NT; nt++){
    int h = nt / NTPH;
    float sa = a_s[nt * 16 + sub];
    float sd = a_d[nt * 16 + sub];
    #pragma unroll
    for (int r = 0; r < 4; r++){ ps[h][r] += acc[nt][r] * sa; pd[h][r] += acc[nt][r] * sd; }
  }
  #pragma unroll
  for (int h = 0; h < HEADS; h++)
    #pragma unroll
    for (int r = 0; r < 4; r++)
      #pragma unroll
      for (int d = 1; d < 16; d <<= 1){
        ps[h][r] += __shfl_xor(ps[h][r], d);
        pd[h][r] += __shfl_xor(pd[h][r], d);
      }

  #pragma unroll
  for (int r = 0; r < 4; r++){
    int gr = rbase + wrow + lk * 4 + r;
    if (gr < n){
      #pragma unroll
      for (int nt = 0; nt < NT; nt++)
        Hh[(size_t)gr * J + nt * 16 + sub] = __float2half(acc[nt][r]);
    }
  }
  #pragma unroll
  for (int h = 0; h < HEADS; h++){
    if (sub == h){
      #pragma unroll
      for (int r = 0; r < 4; r++){
        int gr = rbase + wrow + lk * 4 + r;
        if (gr < n){
          asrc[gr * HEADS + h] = ps[h][r];
          adst[gr * HEADS + h] = pd[h][r];
        }
      }
    }
  }
}

// ---------------- aggregation: wave streams GN nodes' edges densely ----------------
template<int HEADS, int C, bool ELU, bool OUT16, int GN>
__global__ __launch_bounds__(256) void agg_k(const __half* __restrict__ Hh,
    const float* __restrict__ asrc, const float* __restrict__ adst,
    const int* __restrict__ row_ptr, const int* __restrict__ esrc,
    const float* __restrict__ bias, void* __restrict__ outv, int n){
  constexpr int J = HEADS * C;
  constexpr int NL = J / 2;     // column lanes (each a half2 pair)
  int wid = blockIdx.x * (blockDim.x >> 6) + (threadIdx.x >> 6);
  int n0 = wid * GN;
  if (n0 >= n) return;
  int lane = threadIdx.x & 63;
  if (lane >= NL) return;
  int c0 = 2 * lane;
  int hh = c0 / C;
  const __half2* hp = (const __half2*)Hh;
  int gcnt = min(GN, n - n0);
  int rp = row_ptr[n0 + min(lane, gcnt)];   // lanes 0..gcnt hold boundaries
  float b0 = bias[c0], b1 = bias[c0 + 1];
  int bkt3 = (n0 & ~255) * HEADS;           // adst base of this bucket
  int e = __shfl(rp, 0);
  int eend = __shfl(rp, gcnt);
  int g = 0;
  int nb = __shfl(rp, 1);
  float acc0 = 0.f, acc1 = 0.f, den = 0.f;
  __half2* outh = (__half2*)outv;
  float* outf = (float*)outv;

  auto finalize = [&](int gg){
    float inv = 1.f / (den + EPS_);
    float r0 = acc0 * inv + b0, r1 = acc1 * inv + b1;
    if (ELU){
      r0 = r0 > 0.f ? r0 : __expf(r0) - 1.f;
      r1 = r1 > 0.f ? r1 : __expf(r1) - 1.f;
    }
    int node = n0 + gg;
    if (OUT16) outh[(size_t)node * NL + lane] = __floats2half2_rn(r0, r1);
    else *reinterpret_cast<float2*>(outf + (size_t)node * J + c0) = make_float2(r0, r1);
    acc0 = 0.f; acc1 = 0.f; den = 0.f;
  };

  for (; e + 8 <= eend; e += 8){
    int ev[8];
    #pragma unroll
    for (int u = 0; u < 8; u++) ev[u] = esrc[e + u];
    float w[8]; float2 f[8];
    #pragma unroll
    for (int u = 0; u < 8; u++){
      int s = ev[u] & 0xFFFF;
      int dl = ((unsigned)ev[u]) >> 16;
      float logit = asrc[s * HEADS + hh] + adst[bkt3 + dl * HEADS + hh];
      w[u] = __expf(lrelu(logit));
      f[u] = __half22float2(hp[(size_t)s * NL + lane]);
    }
    #pragma unroll
    for (int u = 0; u < 8; u++){
      while (e + u >= nb && g < gcnt - 1){ finalize(g); g++; nb = __shfl(rp, g + 1); }
      acc0 += w[u] * f[u].x; acc1 += w[u] * f[u].y; den += w[u];
    }
  }
  for (; e < eend; e++){
    int ev = esrc[e];
    int s = ev & 0xFFFF;
    int dl = ((unsigned)ev) >> 16;
    while (e >= nb && g < gcnt - 1){ finalize(g); g++; nb = __shfl(rp, g + 1); }
    float logit = asrc[s * HEADS + hh] + adst[bkt3 + dl * HEADS + hh];
    float wv = __expf(lrelu(logit));
    float2 f = __half22float2(hp[(size_t)s * NL + lane]);
    acc0 += wv * f.x; acc1 += wv * f.y; den += wv;
  }
  finalize(g);
}

extern "C" void kernel_launch(void* const* d_in, const int* in_sizes, int n_in,
                              void* d_out, int out_size, void* d_ws, size_t ws_size,
                              hipStream_t stream){
  const float* x   = (const float*)d_in[0];
  const int*   ei  = (const int*)  d_in[1];
  const float* W1  = (const float*)d_in[2];
  const float* as1 = (const float*)d_in[3];
  const float* ad1 = (const float*)d_in[4];
  const float* b1  = (const float*)d_in[5];
  const float* W2  = (const float*)d_in[6];
  const float* as2 = (const float*)d_in[7];
  const float* ad2 = (const float*)d_in[8];
  const float* b2  = (const float*)d_in[9];
  const float* W3  = (const float*)d_in[10];
  const float* as3 = (const float*)d_in[11];
  const float* ad3 = (const float*)d_in[12];
  const float* b3  = (const float*)d_in[13];
  float* out = (float*)d_out;

  const int N = N_NODES_C;
  const int E = in_sizes[1] / 2;
  const int* srcv = ei;
  const int* dstv = ei + E;

  char* ws = (char*)d_ws;
  auto alloc = [&](size_t bytes)->char*{ char* p = ws; ws += (bytes + 255) & ~(size_t)255; return p; };
  int*      counts  = (int*)     alloc((size_t)N * 4);
  int*      row_ptr = (int*)     alloc((size_t)(N + 1) * 4);
  int*      csums   = (int*)     alloc(64 * 4);
  int*      bcur    = (int*)     alloc(NBKT * 4);
  int*      esrc    = (int*)     alloc((size_t)(E + N) * 4);
  unsigned* ebuf    = (unsigned*)alloc((size_t)(E + N) * 4);
  __half*   Hh      = (__half*)  alloc((size_t)N * 128 * 2);
  __half*   feat_h  = (__half*)  alloc((size_t)N * 96 * 2);
  float*    a_src   = (float*)   alloc((size_t)N * 3 * 4);
  float*    a_dst   = (float*)   alloc((size_t)N * 3 * 4);
  uint4*    Wf1     = (uint4*)   alloc(128 * 96 * 2);
  uint4*    Wf2     = (uint4*)   alloc(96 * 96 * 2);
  uint4*    Wf3     = (uint4*)   alloc(96 * 128 * 2);

  // ---- CSR (by dst) incl. self-loops, bucketed build ----
  cinit_k<<<(N + 255) / 256, 256, 0, stream>>>(counts, N);
  hist_k<<<(E + 255) / 256, 256, 0, stream>>>(dstv, counts, E);
  int nch = (N + 1023) / 1024;
  chunksum_k<<<nch, 256, 0, stream>>>(counts, csums, N);
  scan_k<<<nch, 1024, 0, stream>>>(counts, csums, row_ptr, bcur, nch, N);
  bucket_k<<<(E + N + BATCH - 1) / BATCH, 256, 0, stream>>>(srcv, dstv, bcur, ebuf, E, N);
  bsort_k<<<NBKT, 256, 0, stream>>>(ebuf, row_ptr, esrc, N);

  // ---- W repacks (one launch) ----
  wpack_all_k<<<17, 256, 0, stream>>>(W1, W2, W3, Wf1, Wf2, Wf3);

  const int GN = 8;
  int gagg = ((N + GN - 1) / GN + 3) / 4;   // 4 waves per block
  int ggemm = (N + 63) / 64;

  // ---- layer 1: 128 -> (3,32), concat, ELU ----
  gemm_mfma_k<128, 96, 3, false><<<ggemm, 256, 0, stream>>>(x, Wf1, as1, ad1, Hh, a_src, a_dst, N);
  agg_k<3, 32, true, true, GN><<<gagg, 256, 0, stream>>>(Hh, a_src, a_dst, row_ptr, esrc, b1, feat_h, N);

  // ---- layer 2: 96 -> (3,32), concat, ELU ----
  gemm_mfma_k<96, 96, 3, true><<<ggemm, 256, 0, stream>>>(feat_h, Wf2, as2, ad2, Hh, a_src, a_dst, N);
  agg_k<3, 32, true, true, GN><<<gagg, 256, 0, stream>>>(Hh, a_src, a_dst, row_ptr, esrc, b2, feat_h, N);

  // ---- layer 3: 96 -> (1,128), mean(=identity for 1 head), no ELU ----
  gemm_mfma_k<96, 128, 1, true><<<ggemm, 256, 0, stream>>>(feat_h, Wf3, as3, ad3, Hh, a_src, a_dst, N);
  agg_k<1, 128, false, false, GN><<<gagg, 256, 0, stream>>>(Hh, a_src, a_dst, row_ptr, esrc, b3, out, N);
}

// Round 13
// 359.684 us; speedup vs baseline: 1.1793x; 1.1793x over previous
//
#include <hip/hip_runtime.h>
#include <hip/hip_bf16.h>
#include <hip/hip_fp16.h>
#include <math.h>

#define N_NODES_C 50000
#define NBKT ((N_NODES_C + 255) / 256)   // 196 buckets of 256 nodes
#define NEG_SLOPE 0.2f
#define EPS_ 1e-16f

typedef _Float16 f16x8 __attribute__((ext_vector_type(8)));
typedef float    f32x4 __attribute__((ext_vector_type(4)));

__device__ __forceinline__ float lrelu(float x){ return x > 0.f ? x : NEG_SLOPE * x; }

// ---------------- CSR build ----------------
__global__ void cinit_k(int* __restrict__ counts, int n){
  int t = blockIdx.x * blockDim.x + threadIdx.x;
  if (t < n) counts[t] = 1;              // rank 0 of every node = its self-loop
}

__global__ void hist_k(const int* __restrict__ dstv, int* __restrict__ counts, int E){
  int t = blockIdx.x * blockDim.x + threadIdx.x;
  if (t < E) atomicAdd(&counts[dstv[t]], 1);
}

__global__ void chunksum_k(const int* __restrict__ counts, int* __restrict__ sums, int n){
  __shared__ int lds[4];
  int base = blockIdx.x * 1024;
  int t = threadIdx.x; // 256
  int s = 0;
  for (int i = t; i < 1024; i += 256){ int idx = base + i; s += (idx < n) ? counts[idx] : 0; }
  for (int d = 32; d >= 1; d >>= 1) s += __shfl_xor(s, d);
  if ((t & 63) == 0) lds[t >> 6] = s;
  __syncthreads();
  if (t == 0) sums[blockIdx.x] = lds[0] + lds[1] + lds[2] + lds[3];
}

// scan with fused chunk-offset (csums sum) and bcur init. nch <= 64.
__global__ void scan_k(const int* __restrict__ counts, const int* __restrict__ csums,
                       int* __restrict__ row_ptr, int* __restrict__ bcur, int nch, int n){
  __shared__ int ws[16];
  __shared__ int boff;
  int base = blockIdx.x * 1024; int t = threadIdx.x; int idx = base + t;
  int v = (idx < n) ? counts[idx] : 0;
  int lane = t & 63, wid = t >> 6;
  int x = v;
  for (int d = 1; d < 64; d <<= 1){ int y = __shfl_up(x, d); if (lane >= d) x += y; }
  if (lane == 63) ws[wid] = x;
  if (t < 64){
    int c = (t < blockIdx.x) ? csums[t] : 0;
    for (int d = 32; d >= 1; d >>= 1) c += __shfl_xor(c, d);
    if (t == 0) boff = c;
  }
  __syncthreads();
  if (t < 16){ int y = ws[t]; for (int d = 1; d < 16; d <<= 1){ int z = __shfl_up(y, d); if (t >= d) y += z; } ws[t] = y; }
  __syncthreads();
  int excl = x - v + (wid ? ws[wid - 1] : 0) + boff;
  if (idx < n){
    row_ptr[idx] = excl;
    if ((idx & 255) == 0) bcur[idx >> 8] = excl;
  }
  if (blockIdx.x == nch - 1 && t == 0) row_ptr[n] = boff + ws[15];
}

// self-loop entries written directly at rank 0 (addresses monotonic)
__global__ void selfwrite_k(const int* __restrict__ row_ptr, int* __restrict__ esrc, int n){
  int v = blockIdx.x * blockDim.x + threadIdx.x;
  if (v < n) esrc[row_ptr[v]] = (int)(((unsigned)(v & 255) << 16) | (unsigned)v);
}

// phase 1: classify REAL edges into dst-buckets with LDS staging.
// entry = src | (dst & 255) << 16
#define BATCH 2048
#define BCAP 32
__global__ __launch_bounds__(256) void bucket_k(const int* __restrict__ srcv, const int* __restrict__ dstv,
                                                int* __restrict__ bcur, unsigned* __restrict__ ebuf, int E){
  __shared__ unsigned stage[NBKT * BCAP];   // 25 KB
  __shared__ int cnt[NBKT];
  int t = threadIdx.x;
  int start = blockIdx.x * BATCH;
  int end = start + BATCH; if (end > E) end = E;
  for (int i = t; i < NBKT; i += 256) cnt[i] = 0;
  __syncthreads();
  for (int e = start + t; e < end; e += 256){
    int s = srcv[e], d = dstv[e];
    int b = d >> 8;
    unsigned entry = (unsigned)s | ((unsigned)(d & 255) << 16);
    int pos = atomicAdd(&cnt[b], 1);
    if (pos < BCAP) stage[b * BCAP + pos] = entry;
    else { int p = atomicAdd(&bcur[b], 1); ebuf[p] = entry; }   // rare overflow
  }
  __syncthreads();
  if (t < NBKT){
    int c = cnt[t]; if (c > BCAP) c = BCAP;
    if (c > 0){
      int p = atomicAdd(&bcur[t], c);
      for (int i = 0; i < c; i++) ebuf[p + i] = stage[t * BCAP + i];
    }
  }
}

// phase 2: one block owns one bucket; rank real edges per node starting at 1.
__global__ __launch_bounds__(256) void bsort_k(const unsigned* __restrict__ ebuf,
                                               const int* __restrict__ row_ptr,
                                               int* __restrict__ esrc, int n){
  __shared__ int cnt[256];
  int b = blockIdx.x;
  int nb = b * 256;
  int t = threadIdx.x;
  cnt[t] = 1;                        // rank 0 = self-loop
  __syncthreads();
  int hi_node = nb + 256; if (hi_node > n) hi_node = n;
  int beg = row_ptr[nb], end = row_ptr[hi_node];
  int realcnt = (end - beg) - (hi_node - nb);
  for (int i = beg + t; i < beg + realcnt; i += 256){
    unsigned e = ebuf[i];
    int dl = e >> 16;
    int rank = atomicAdd(&cnt[dl], 1);
    esrc[row_ptr[nb + dl] + rank] = (int)e;   // keep (dl<<16)|src
  }
}

// ---------------- W repack to MFMA B-fragment order (fp16), all 3 in one launch ----------------
template<int K, int J>
__device__ void wpack_dev(const float* __restrict__ W, uint4* __restrict__ Wf, int blk, int nblk){
  constexpr int KS = K / 32, NT = J / 16;
  int tot = KS * NT * 64;
  for (int t = blk * 256 + threadIdx.x; t < tot; t += nblk * 256){
    int l = t & 63;
    int nt = (t >> 6) % NT;
    int kk = t / (64 * NT);
    int col = nt * 16 + (l & 15);
    int k0 = kk * 32 + (l >> 4) * 8;
    unsigned u[4];
    #pragma unroll
    for (int p = 0; p < 4; p++){
      __half2 h = __floats2half2_rn(W[(k0 + 2 * p) * J + col], W[(k0 + 2 * p + 1) * J + col]);
      u[p] = *reinterpret_cast<unsigned*>(&h);
    }
    uint4 v; v.x = u[0]; v.y = u[1]; v.z = u[2]; v.w = u[3];
    Wf[t] = v;
  }
}

__global__ void wpack_all_k(const float* W1, const float* W2, const float* W3,
                            uint4* Wf1, uint4* Wf2, uint4* Wf3){
  int b = blockIdx.x;
  if (b < 6) wpack_dev<128, 96>(W1, Wf1, b, 6);
  else if (b < 11) wpack_dev<96, 96>(W2, Wf2, b - 6, 5);
  else wpack_dev<96, 128>(W3, Wf3, b - 11, 6);
}

// ---------------- MFMA GEMM + alpha ----------------
template<int K, int J, int HEADS, bool AF16>
__global__ __launch_bounds__(256) void gemm_mfma_k(
    const void* __restrict__ Ain, const uint4* __restrict__ Wf,
    const float* __restrict__ a_s, const float* __restrict__ a_d,
    __half* __restrict__ Hh, float* __restrict__ asrc, float* __restrict__ adst, int n){
  constexpr int KS = K / 32;
  constexpr int NT = J / 16;
  constexpr int CPR = K / 8;
  constexpr int NTPH = NT / HEADS;
  __shared__ uint4 Alds[64 * 16];
  int t = threadIdx.x;
  int rbase = blockIdx.x * 64;

  for (int i = t; i < 64 * CPR; i += 256){
    int r = i / CPR, c = i % CPR;
    int gr = rbase + r;
    uint4 v = make_uint4(0u, 0u, 0u, 0u);
    if (gr < n){
      if (AF16){
        v = ((const uint4*)Ain)[(size_t)gr * CPR + c];
      } else {
        const float4* af = (const float4*)Ain + (size_t)gr * (K / 4) + c * 2;
        float4 lo = af[0], hi = af[1];
        __half2 p0 = __floats2half2_rn(lo.x, lo.y);
        __half2 p1 = __floats2half2_rn(lo.z, lo.w);
        __half2 p2 = __floats2half2_rn(hi.x, hi.y);
        __half2 p3 = __floats2half2_rn(hi.z, hi.w);
        v.x = *reinterpret_cast<unsigned*>(&p0);
        v.y = *reinterpret_cast<unsigned*>(&p1);
        v.z = *reinterpret_cast<unsigned*>(&p2);
        v.w = *reinterpret_cast<unsigned*>(&p3);
      }
    }
    Alds[r * 16 + (c ^ (r & 7))] = v;
  }
  __syncthreads();

  int l = t & 63;
  int wrow = (t >> 6) * 16;
  int sub = l & 15;
  int lk = l >> 4;
  f32x4 acc[NT];
  #pragma unroll
  for (int i = 0; i < NT; i++) acc[i] = (f32x4){0.f, 0.f, 0.f, 0.f};

  for (int kk = 0; kk < KS; kk++){
    int trow = wrow + sub;
    int c = kk * 4 + lk;
    f16x8 a = *reinterpret_cast<const f16x8*>(&Alds[trow * 16 + (c ^ (trow & 7))]);
    const uint4* wb = Wf + (size_t)(kk * NT) * 64 + l;
    #pragma unroll
    for (int nt = 0; nt < NT; nt++){
      uint4 wv = wb[nt * 64];
      f16x8 bfr = *reinterpret_cast<const f16x8*>(&wv);
      acc[nt] = __builtin_amdgcn_mfma_f32_16x16x32_f16(a, bfr, acc[nt], 0, 0, 0);
    }
  }

  float ps[HEADS][4], pd[HEADS][4];
  #pragma unroll
  for (int h = 0; h < HEADS; h++)
    #pragma unroll
    for (int r = 0; r < 4; r++){ ps[h][r] = 0.f; pd[h][r] = 0.f; }
  #pragma unroll
  for (int nt = 0; nt < NT; nt++){
    int h = nt / NTPH;
    float sa = a_s[nt * 16 + sub];
    float sd = a_d[nt * 16 + sub];
    #pragma unroll
    for (int r = 0; r < 4; r++){ ps[h][r] += acc[nt][r] * sa; pd[h][r] += acc[nt][r] * sd; }
  }
  #pragma unroll
  for (int h = 0; h < HEADS; h++)
    #pragma unroll
    for (int r = 0; r < 4; r++)
      #pragma unroll
      for (int d = 1; d < 16; d <<= 1){
        ps[h][r] += __shfl_xor(ps[h][r], d);
        pd[h][r] += __shfl_xor(pd[h][r], d);
      }

  #pragma unroll
  for (int r = 0; r < 4; r++){
    int gr = rbase + wrow + lk * 4 + r;
    if (gr < n){
      #pragma unroll
      for (int nt = 0; nt < NT; nt++)
        Hh[(size_t)gr * J + nt * 16 + sub] = __float2half(acc[nt][r]);
    }
  }
  #pragma unroll
  for (int h = 0; h < HEADS; h++){
    if (sub == h){
      #pragma unroll
      for (int r = 0; r < 4; r++){
        int gr = rbase + wrow + lk * 4 + r;
        if (gr < n){
          asrc[gr * HEADS + h] = ps[h][r];
          adst[gr * HEADS + h] = pd[h][r];
        }
      }
    }
  }
}

// ---------------- aggregation: wave streams GN nodes' edges densely ----------------
template<int HEADS, int C, bool ELU, bool OUT16, int GN>
__global__ __launch_bounds__(256) void agg_k(const __half* __restrict__ Hh,
    const float* __restrict__ asrc, const float* __restrict__ adst,
    const int* __restrict__ row_ptr, const int* __restrict__ esrc,
    const float* __restrict__ bias, void* __restrict__ outv, int n){
  constexpr int J = HEADS * C;
  constexpr int NL = J / 2;     // column lanes (each a half2 pair)
  int wid = blockIdx.x * (blockDim.x >> 6) + (threadIdx.x >> 6);
  int n0 = wid * GN;
  if (n0 >= n) return;
  int lane = threadIdx.x & 63;
  if (lane >= NL) return;
  int c0 = 2 * lane;
  int hh = c0 / C;
  const __half2* hp = (const __half2*)Hh;
  int gcnt = min(GN, n - n0);
  int rp = row_ptr[n0 + min(lane, gcnt)];   // lanes 0..gcnt hold boundaries
  float b0 = bias[c0], b1 = bias[c0 + 1];
  int bkt3 = (n0 & ~255) * HEADS;           // adst base of this bucket
  int e = __shfl(rp, 0);
  int eend = __shfl(rp, gcnt);
  int g = 0;
  int nb = __shfl(rp, 1);
  float acc0 = 0.f, acc1 = 0.f, den = 0.f;
  __half2* outh = (__half2*)outv;
  float* outf = (float*)outv;

  auto finalize = [&](int gg){
    float inv = 1.f / (den + EPS_);
    float r0 = acc0 * inv + b0, r1 = acc1 * inv + b1;
    if (ELU){
      r0 = r0 > 0.f ? r0 : __expf(r0) - 1.f;
      r1 = r1 > 0.f ? r1 : __expf(r1) - 1.f;
    }
    int node = n0 + gg;
    if (OUT16) outh[(size_t)node * NL + lane] = __floats2half2_rn(r0, r1);
    else *reinterpret_cast<float2*>(outf + (size_t)node * J + c0) = make_float2(r0, r1);
    acc0 = 0.f; acc1 = 0.f; den = 0.f;
  };

  for (; e + 8 <= eend; e += 8){
    int ev[8];
    #pragma unroll
    for (int u = 0; u < 8; u++) ev[u] = esrc[e + u];
    float w[8]; float2 f[8];
    #pragma unroll
    for (int u = 0; u < 8; u++){
      int s = ev[u] & 0xFFFF;
      int dl = ((unsigned)ev[u]) >> 16;
      float logit = asrc[s * HEADS + hh] + adst[bkt3 + dl * HEADS + hh];
      w[u] = __expf(lrelu(logit));
      f[u] = __half22float2(hp[(size_t)s * NL + lane]);
    }
    #pragma unroll
    for (int u = 0; u < 8; u++){
      while (e + u >= nb && g < gcnt - 1){ finalize(g); g++; nb = __shfl(rp, g + 1); }
      acc0 += w[u] * f[u].x; acc1 += w[u] * f[u].y; den += w[u];
    }
  }
  for (; e < eend; e++){
    int ev = esrc[e];
    int s = ev & 0xFFFF;
    int dl = ((unsigned)ev) >> 16;
    while (e >= nb && g < gcnt - 1){ finalize(g); g++; nb = __shfl(rp, g + 1); }
    float logit = asrc[s * HEADS + hh] + adst[bkt3 + dl * HEADS + hh];
    float wv = __expf(lrelu(logit));
    float2 f = __half22float2(hp[(size_t)s * NL + lane]);
    acc0 += wv * f.x; acc1 += wv * f.y; den += wv;
  }
  finalize(g);
}

extern "C" void kernel_launch(void* const* d_in, const int* in_sizes, int n_in,
                              void* d_out, int out_size, void* d_ws, size_t ws_size,
                              hipStream_t stream){
  const float* x   = (const float*)d_in[0];
  const int*   ei  = (const int*)  d_in[1];
  const float* W1  = (const float*)d_in[2];
  const float* as1 = (const float*)d_in[3];
  const float* ad1 = (const float*)d_in[4];
  const float* b1  = (const float*)d_in[5];
  const float* W2  = (const float*)d_in[6];
  const float* as2 = (const float*)d_in[7];
  const float* ad2 = (const float*)d_in[8];
  const float* b2  = (const float*)d_in[9];
  const float* W3  = (const float*)d_in[10];
  const float* as3 = (const float*)d_in[11];
  const float* ad3 = (const float*)d_in[12];
  const float* b3  = (const float*)d_in[13];
  float* out = (float*)d_out;

  const int N = N_NODES_C;
  const int E = in_sizes[1] / 2;
  const int* srcv = ei;
  const int* dstv = ei + E;

  char* ws = (char*)d_ws;
  auto alloc = [&](size_t bytes)->char*{ char* p = ws; ws += (bytes + 255) & ~(size_t)255; return p; };
  int*      counts  = (int*)     alloc((size_t)N * 4);
  int*      row_ptr = (int*)     alloc((size_t)(N + 1) * 4);
  int*      csums   = (int*)     alloc(64 * 4);
  int*      bcur    = (int*)     alloc(NBKT * 4);
  int*      esrc    = (int*)     alloc((size_t)(E + N) * 4);
  unsigned* ebuf    = (unsigned*)alloc((size_t)(E + N) * 4);
  __half*   Hh      = (__half*)  alloc((size_t)N * 128 * 2);
  __half*   feat_h  = (__half*)  alloc((size_t)N * 96 * 2);
  float*    a_src   = (float*)   alloc((size_t)N * 3 * 4);
  float*    a_dst   = (float*)   alloc((size_t)N * 3 * 4);
  uint4*    Wf1     = (uint4*)   alloc(128 * 96 * 2);
  uint4*    Wf2     = (uint4*)   alloc(96 * 96 * 2);
  uint4*    Wf3     = (uint4*)   alloc(96 * 128 * 2);

  // ---- CSR (by dst) incl. self-loops; only REAL edges go through the bucketer ----
  cinit_k<<<(N + 255) / 256, 256, 0, stream>>>(counts, N);
  hist_k<<<(E + 255) / 256, 256, 0, stream>>>(dstv, counts, E);
  int nch = (N + 1023) / 1024;
  chunksum_k<<<nch, 256, 0, stream>>>(counts, csums, N);
  scan_k<<<nch, 1024, 0, stream>>>(counts, csums, row_ptr, bcur, nch, N);
  selfwrite_k<<<(N + 255) / 256, 256, 0, stream>>>(row_ptr, esrc, N);
  bucket_k<<<(E + BATCH - 1) / BATCH, 256, 0, stream>>>(srcv, dstv, bcur, ebuf, E);
  bsort_k<<<NBKT, 256, 0, stream>>>(ebuf, row_ptr, esrc, N);

  // ---- W repacks (one launch) ----
  wpack_all_k<<<17, 256, 0, stream>>>(W1, W2, W3, Wf1, Wf2, Wf3);

  const int GN = 8;
  int gagg = ((N + GN - 1) / GN + 3) / 4;   // 4 waves per block
  int ggemm = (N + 63) / 64;

  // ---- layer 1: 128 -> (3,32), concat, ELU ----
  gemm_mfma_k<128, 96, 3, false><<<ggemm, 256, 0, stream>>>(x, Wf1, as1, ad1, Hh, a_src, a_dst, N);
  agg_k<3, 32, true, true, GN><<<gagg, 256, 0, stream>>>(Hh, a_src, a_dst, row_ptr, esrc, b1, feat_h, N);

  // ---- layer 2: 96 -> (3,32), concat, ELU ----
  gemm_mfma_k<96, 96, 3, true><<<ggemm, 256, 0, stream>>>(feat_h, Wf2, as2, ad2, Hh, a_src, a_dst, N);
  agg_k<3, 32, true, true, GN><<<gagg, 256, 0, stream>>>(Hh, a_src, a_dst, row_ptr, esrc, b2, feat_h, N);

  // ---- layer 3: 96 -> (1,128), mean(=identity for 1 head), no ELU ----
  gemm_mfma_k<96, 128, 1, true><<<ggemm, 256, 0, stream>>>(feat_h, Wf3, as3, ad3, Hh, a_src, a_dst, N);
  agg_k<1, 128, false, false, GN><<<gagg, 256, 0, stream>>>(Hh, a_src, a_dst, row_ptr, esrc, b3, out, N);
}

// Round 14
// 329.727 us; speedup vs baseline: 1.2864x; 1.0909x over previous
//
#include <hip/hip_runtime.h>
#include <hip/hip_bf16.h>
#include <hip/hip_fp16.h>
#include <math.h>

#define N_NODES_C 50000
#define NBKT ((N_NODES_C + 255) / 256)   // 196 buckets of 256 nodes
#define NEG_SLOPE 0.2f
#define EPS_ 1e-16f

typedef _Float16 f16x8 __attribute__((ext_vector_type(8)));
typedef float    f32x4 __attribute__((ext_vector_type(4)));

__device__ __forceinline__ float lrelu(float x){ return x > 0.f ? x : NEG_SLOPE * x; }

// ---------------- CSR build ----------------
__global__ void cinit_k(int* __restrict__ counts, int n){
  int t = blockIdx.x * blockDim.x + threadIdx.x;
  if (t < n) counts[t] = 1;              // rank 0 of every node = its self-loop
}

__global__ void hist_k(const int* __restrict__ dstv, int* __restrict__ counts, int E){
  int t = blockIdx.x * blockDim.x + threadIdx.x;
  if (t < E) atomicAdd(&counts[dstv[t]], 1);
}

__global__ void chunksum_k(const int* __restrict__ counts, int* __restrict__ sums, int n){
  __shared__ int lds[4];
  int base = blockIdx.x * 1024;
  int t = threadIdx.x; // 256
  int s = 0;
  for (int i = t; i < 1024; i += 256){ int idx = base + i; s += (idx < n) ? counts[idx] : 0; }
  for (int d = 32; d >= 1; d >>= 1) s += __shfl_xor(s, d);
  if ((t & 63) == 0) lds[t >> 6] = s;
  __syncthreads();
  if (t == 0) sums[blockIdx.x] = lds[0] + lds[1] + lds[2] + lds[3];
}

// scan with fused chunk-offset (csums sum) and bcur init. nch <= 64.
__global__ void scan_k(const int* __restrict__ counts, const int* __restrict__ csums,
                       int* __restrict__ row_ptr, int* __restrict__ bcur, int nch, int n){
  __shared__ int ws[16];
  __shared__ int boff;
  int base = blockIdx.x * 1024; int t = threadIdx.x; int idx = base + t;
  int v = (idx < n) ? counts[idx] : 0;
  int lane = t & 63, wid = t >> 6;
  int x = v;
  for (int d = 1; d < 64; d <<= 1){ int y = __shfl_up(x, d); if (lane >= d) x += y; }
  if (lane == 63) ws[wid] = x;
  if (t < 64){
    int c = (t < blockIdx.x) ? csums[t] : 0;
    for (int d = 32; d >= 1; d >>= 1) c += __shfl_xor(c, d);
    if (t == 0) boff = c;
  }
  __syncthreads();
  if (t < 16){ int y = ws[t]; for (int d = 1; d < 16; d <<= 1){ int z = __shfl_up(y, d); if (t >= d) y += z; } ws[t] = y; }
  __syncthreads();
  int excl = x - v + (wid ? ws[wid - 1] : 0) + boff;
  if (idx < n){
    row_ptr[idx] = excl;
    if ((idx & 255) == 0) bcur[idx >> 8] = excl;
  }
  if (blockIdx.x == nch - 1 && t == 0) row_ptr[n] = boff + ws[15];
}

// self-loop entries written directly at rank 0 (addresses monotonic)
__global__ void selfwrite_k(const int* __restrict__ row_ptr, int* __restrict__ esrc, int n){
  int v = blockIdx.x * blockDim.x + threadIdx.x;
  if (v < n) esrc[row_ptr[v]] = v;
}

// phase 1: classify REAL edges into dst-buckets with LDS staging.
// entry = src | (dst & 255) << 16
#define BATCH 2048
#define BCAP 32
__global__ __launch_bounds__(256) void bucket_k(const int* __restrict__ srcv, const int* __restrict__ dstv,
                                                int* __restrict__ bcur, unsigned* __restrict__ ebuf, int E){
  __shared__ unsigned stage[NBKT * BCAP];   // 25 KB
  __shared__ int cnt[NBKT];
  int t = threadIdx.x;
  int start = blockIdx.x * BATCH;
  int end = start + BATCH; if (end > E) end = E;
  for (int i = t; i < NBKT; i += 256) cnt[i] = 0;
  __syncthreads();
  for (int e = start + t; e < end; e += 256){
    int s = srcv[e], d = dstv[e];
    int b = d >> 8;
    unsigned entry = (unsigned)s | ((unsigned)(d & 255) << 16);
    int pos = atomicAdd(&cnt[b], 1);
    if (pos < BCAP) stage[b * BCAP + pos] = entry;
    else { int p = atomicAdd(&bcur[b], 1); ebuf[p] = entry; }   // rare overflow
  }
  __syncthreads();
  if (t < NBKT){
    int c = cnt[t]; if (c > BCAP) c = BCAP;
    if (c > 0){
      int p = atomicAdd(&bcur[t], c);
      for (int i = 0; i < c; i++) ebuf[p + i] = stage[t * BCAP + i];
    }
  }
}

// phase 2: one block owns one bucket; rank real edges per node starting at 1; store plain src.
__global__ __launch_bounds__(256) void bsort_k(const unsigned* __restrict__ ebuf,
                                               const int* __restrict__ row_ptr,
                                               int* __restrict__ esrc, int n){
  __shared__ int cnt[256];
  int b = blockIdx.x;
  int nb = b * 256;
  int t = threadIdx.x;
  cnt[t] = 1;                        // rank 0 = self-loop
  __syncthreads();
  int hi_node = nb + 256; if (hi_node > n) hi_node = n;
  int beg = row_ptr[nb], end = row_ptr[hi_node];
  int realcnt = (end - beg) - (hi_node - nb);
  for (int i = beg + t; i < beg + realcnt; i += 256){
    unsigned e = ebuf[i];
    int dl = e >> 16;
    int rank = atomicAdd(&cnt[dl], 1);
    esrc[row_ptr[nb + dl] + rank] = (int)(e & 0xFFFFu);
  }
}

// ---------------- W repack to MFMA B-fragment order (fp16), all 3 in one launch ----------------
template<int K, int J>
__device__ void wpack_dev(const float* __restrict__ W, uint4* __restrict__ Wf, int blk, int nblk){
  constexpr int KS = K / 32, NT = J / 16;
  int tot = KS * NT * 64;
  for (int t = blk * 256 + threadIdx.x; t < tot; t += nblk * 256){
    int l = t & 63;
    int nt = (t >> 6) % NT;
    int kk = t / (64 * NT);
    int col = nt * 16 + (l & 15);
    int k0 = kk * 32 + (l >> 4) * 8;
    unsigned u[4];
    #pragma unroll
    for (int p = 0; p < 4; p++){
      __half2 h = __floats2half2_rn(W[(k0 + 2 * p) * J + col], W[(k0 + 2 * p + 1) * J + col]);
      u[p] = *reinterpret_cast<unsigned*>(&h);
    }
    uint4 v; v.x = u[0]; v.y = u[1]; v.z = u[2]; v.w = u[3];
    Wf[t] = v;
  }
}

__global__ void wpack_all_k(const float* W1, const float* W2, const float* W3,
                            uint4* Wf1, uint4* Wf2, uint4* Wf3){
  int b = blockIdx.x;
  if (b < 6) wpack_dev<128, 96>(W1, Wf1, b, 6);
  else if (b < 11) wpack_dev<96, 96>(W2, Wf2, b - 6, 5);
  else wpack_dev<96, 128>(W3, Wf3, b - 11, 6);
}

// ---------------- MFMA GEMM + alpha ----------------
template<int K, int J, int HEADS, bool AF16>
__global__ __launch_bounds__(256) void gemm_mfma_k(
    const void* __restrict__ Ain, const uint4* __restrict__ Wf,
    const float* __restrict__ a_s, const float* __restrict__ a_d,
    __half* __restrict__ Hh, float* __restrict__ asrc, float* __restrict__ adst, int n){
  constexpr int KS = K / 32;
  constexpr int NT = J / 16;
  constexpr int CPR = K / 8;
  constexpr int NTPH = NT / HEADS;
  __shared__ uint4 Alds[64 * 16];
  int t = threadIdx.x;
  int rbase = blockIdx.x * 64;

  for (int i = t; i < 64 * CPR; i += 256){
    int r = i / CPR, c = i % CPR;
    int gr = rbase + r;
    uint4 v = make_uint4(0u, 0u, 0u, 0u);
    if (gr < n){
      if (AF16){
        v = ((const uint4*)Ain)[(size_t)gr * CPR + c];
      } else {
        const float4* af = (const float4*)Ain + (size_t)gr * (K / 4) + c * 2;
        float4 lo = af[0], hi = af[1];
        __half2 p0 = __floats2half2_rn(lo.x, lo.y);
        __half2 p1 = __floats2half2_rn(lo.z, lo.w);
        __half2 p2 = __floats2half2_rn(hi.x, hi.y);
        __half2 p3 = __floats2half2_rn(hi.z, hi.w);
        v.x = *reinterpret_cast<unsigned*>(&p0);
        v.y = *reinterpret_cast<unsigned*>(&p1);
        v.z = *reinterpret_cast<unsigned*>(&p2);
        v.w = *reinterpret_cast<unsigned*>(&p3);
      }
    }
    Alds[r * 16 + (c ^ (r & 7))] = v;
  }
  __syncthreads();

  int l = t & 63;
  int wrow = (t >> 6) * 16;
  int sub = l & 15;
  int lk = l >> 4;
  f32x4 acc[NT];
  #pragma unroll
  for (int i = 0; i < NT; i++) acc[i] = (f32x4){0.f, 0.f, 0.f, 0.f};

  for (int kk = 0; kk < KS; kk++){
    int trow = wrow + sub;
    int c = kk * 4 + lk;
    f16x8 a = *reinterpret_cast<const f16x8*>(&Alds[trow * 16 + (c ^ (trow & 7))]);
    const uint4* wb = Wf + (size_t)(kk * NT) * 64 + l;
    #pragma unroll
    for (int nt = 0; nt < NT; nt++){
      uint4 wv = wb[nt * 64];
      f16x8 bfr = *reinterpret_cast<const f16x8*>(&wv);
      acc[nt] = __builtin_amdgcn_mfma_f32_16x16x32_f16(a, bfr, acc[nt], 0, 0, 0);
    }
  }

  float ps[HEADS][4], pd[HEADS][4];
  #pragma unroll
  for (int h = 0; h < HEADS; h++)
    #pragma unroll
    for (int r = 0; r < 4; r++){ ps[h][r] = 0.f; pd[h][r] = 0.f; }
  #pragma unroll
  for (int nt = 0; nt < NT; nt++){
    int h = nt / NTPH;
    float sa = a_s[nt * 16 + sub];
    float sd = a_d[nt * 16 + sub];
    #pragma unroll
    for (int r = 0; r < 4; r++){ ps[h][r] += acc[nt][r] * sa; pd[h][r] += acc[nt][r] * sd; }
  }
  #pragma unroll
  for (int h = 0; h < HEADS; h++)
    #pragma unroll
    for (int r = 0; r < 4; r++)
      #pragma unroll
      for (int d = 1; d < 16; d <<= 1){
        ps[h][r] += __shfl_xor(ps[h][r], d);
        pd[h][r] += __shfl_xor(pd[h][r], d);
      }

  #pragma unroll
  for (int r = 0; r < 4; r++){
    int gr = rbase + wrow + lk * 4 + r;
    if (gr < n){
      #pragma unroll
      for (int nt = 0; nt < NT; nt++)
        Hh[(size_t)gr * J + nt * 16 + sub] = __float2half(acc[nt][r]);
    }
  }
  #pragma unroll
  for (int h = 0; h < HEADS; h++){
    if (sub == h){
      #pragma unroll
      for (int r = 0; r < 4; r++){
        int gr = rbase + wrow + lk * 4 + r;
        if (gr < n){
          asrc[gr * HEADS + h] = ps[h][r];
          adst[gr * HEADS + h] = pd[h][r];
        }
      }
    }
  }
}

// ---------------- aggregation: wave per node, 8-edge masked strips, 16 gathers in flight ----------------
template<int HEADS, int C, bool ELU, bool OUT16>
__global__ __launch_bounds__(256) void agg_k(const __half* __restrict__ Hh,
    const float* __restrict__ asrc, const float* __restrict__ adst,
    const int* __restrict__ row_ptr, const int* __restrict__ esrc,
    const float* __restrict__ bias, void* __restrict__ outv, int n){
  constexpr int J = HEADS * C;
  constexpr int NL = J / 2;
  int node = blockIdx.x * (blockDim.x >> 6) + (threadIdx.x >> 6);
  if (node >= n) return;
  int lane = threadIdx.x & 63;
  bool colact = (NL == 64) || (lane < NL);
  int cl = colact ? lane : (NL - 1);
  int c0 = 2 * cl;
  int hh = c0 / C;
  const __half2* hp = (const __half2*)Hh;
  float ad = adst[node * HEADS + hh];
  int beg = row_ptr[node], end = row_ptr[node + 1];
  float acc0 = 0.f, acc1 = 0.f, den = 0.f;

  for (int e0 = beg; e0 < end; e0 += 8){
    int rem = end - e0;     // >= 1
    int s[8];
    #pragma unroll
    for (int u = 0; u < 8; u++) s[u] = esrc[e0 + ((u < rem) ? u : (rem - 1))];
    float wa[8];
    #pragma unroll
    for (int u = 0; u < 8; u++) wa[u] = asrc[s[u] * HEADS + hh];   // 8 alpha gathers in flight
    float2 f[8];
    #pragma unroll
    for (int u = 0; u < 8; u++) f[u] = __half22float2(hp[(size_t)s[u] * NL + cl]); // 8 feature gathers
    #pragma unroll
    for (int u = 0; u < 8; u++){
      float wv = (u < rem) ? __expf(lrelu(wa[u] + ad)) : 0.f;
      acc0 += wv * f[u].x; acc1 += wv * f[u].y; den += wv;
    }
  }
  if (colact){
    float inv = 1.f / (den + EPS_);
    float r0 = acc0 * inv + bias[c0];
    float r1 = acc1 * inv + bias[c0 + 1];
    if (ELU){
      r0 = r0 > 0.f ? r0 : __expf(r0) - 1.f;
      r1 = r1 > 0.f ? r1 : __expf(r1) - 1.f;
    }
    if (OUT16) ((__half2*)outv)[(size_t)node * NL + cl] = __floats2half2_rn(r0, r1);
    else *reinterpret_cast<float2*>((float*)outv + (size_t)node * J + c0) = make_float2(r0, r1);
  }
}

extern "C" void kernel_launch(void* const* d_in, const int* in_sizes, int n_in,
                              void* d_out, int out_size, void* d_ws, size_t ws_size,
                              hipStream_t stream){
  const float* x   = (const float*)d_in[0];
  const int*   ei  = (const int*)  d_in[1];
  const float* W1  = (const float*)d_in[2];
  const float* as1 = (const float*)d_in[3];
  const float* ad1 = (const float*)d_in[4];
  const float* b1  = (const float*)d_in[5];
  const float* W2  = (const float*)d_in[6];
  const float* as2 = (const float*)d_in[7];
  const float* ad2 = (const float*)d_in[8];
  const float* b2  = (const float*)d_in[9];
  const float* W3  = (const float*)d_in[10];
  const float* as3 = (const float*)d_in[11];
  const float* ad3 = (const float*)d_in[12];
  const float* b3  = (const float*)d_in[13];
  float* out = (float*)d_out;

  const int N = N_NODES_C;
  const int E = in_sizes[1] / 2;
  const int* srcv = ei;
  const int* dstv = ei + E;

  char* ws = (char*)d_ws;
  auto alloc = [&](size_t bytes)->char*{ char* p = ws; ws += (bytes + 255) & ~(size_t)255; return p; };
  int*      counts  = (int*)     alloc((size_t)N * 4);
  int*      row_ptr = (int*)     alloc((size_t)(N + 1) * 4);
  int*      csums   = (int*)     alloc(64 * 4);
  int*      bcur    = (int*)     alloc(NBKT * 4);
  int*      esrc    = (int*)     alloc((size_t)(E + N) * 4);
  unsigned* ebuf    = (unsigned*)alloc((size_t)(E + N) * 4);
  __half*   Hh      = (__half*)  alloc((size_t)N * 128 * 2);
  __half*   feat_h  = (__half*)  alloc((size_t)N * 96 * 2);
  float*    a_src   = (float*)   alloc((size_t)N * 3 * 4);
  float*    a_dst   = (float*)   alloc((size_t)N * 3 * 4);
  uint4*    Wf1     = (uint4*)   alloc(128 * 96 * 2);
  uint4*    Wf2     = (uint4*)   alloc(96 * 96 * 2);
  uint4*    Wf3     = (uint4*)   alloc(96 * 128 * 2);

  // ---- CSR (by dst) incl. self-loops; only REAL edges go through the bucketer ----
  cinit_k<<<(N + 255) / 256, 256, 0, stream>>>(counts, N);
  hist_k<<<(E + 255) / 256, 256, 0, stream>>>(dstv, counts, E);
  int nch = (N + 1023) / 1024;
  chunksum_k<<<nch, 256, 0, stream>>>(counts, csums, N);
  scan_k<<<nch, 1024, 0, stream>>>(counts, csums, row_ptr, bcur, nch, N);
  selfwrite_k<<<(N + 255) / 256, 256, 0, stream>>>(row_ptr, esrc, N);
  bucket_k<<<(E + BATCH - 1) / BATCH, 256, 0, stream>>>(srcv, dstv, bcur, ebuf, E);
  bsort_k<<<NBKT, 256, 0, stream>>>(ebuf, row_ptr, esrc, N);

  // ---- W repacks (one launch) ----
  wpack_all_k<<<17, 256, 0, stream>>>(W1, W2, W3, Wf1, Wf2, Wf3);

  int gnode4 = (N + 3) / 4;
  int ggemm  = (N + 63) / 64;

  // ---- layer 1: 128 -> (3,32), concat, ELU ----
  gemm_mfma_k<128, 96, 3, false><<<ggemm, 256, 0, stream>>>(x, Wf1, as1, ad1, Hh, a_src, a_dst, N);
  agg_k<3, 32, true, true><<<gnode4, 256, 0, stream>>>(Hh, a_src, a_dst, row_ptr, esrc, b1, feat_h, N);

  // ---- layer 2: 96 -> (3,32), concat, ELU ----
  gemm_mfma_k<96, 96, 3, true><<<ggemm, 256, 0, stream>>>(feat_h, Wf2, as2, ad2, Hh, a_src, a_dst, N);
  agg_k<3, 32, true, true><<<gnode4, 256, 0, stream>>>(Hh, a_src, a_dst, row_ptr, esrc, b2, feat_h, N);

  // ---- layer 3: 96 -> (1,128), mean(=identity for 1 head), no ELU ----
  gemm_mfma_k<96, 128, 1, true><<<ggemm, 256, 0, stream>>>(feat_h, Wf3, as3, ad3, Hh, a_src, a_dst, N);
  agg_k<1, 128, false, false><<<gnode4, 256, 0, stream>>>(Hh, a_src, a_dst, row_ptr, esrc, b3, out, N);
}